// Round 1
// baseline (907.256 us; speedup 1.0000x reference)
//
#include <hip/hip_runtime.h>

// Problem shape (fixed by setup_inputs): x (16,32,512,512) fp32, params (16,5) fp32,
// small_h = small_w = 256. Output (16,32,256,256) fp32.
constexpr int N_  = 16;
constexpr int C_  = 32;
constexpr int H_  = 512;
constexpr int W_  = 512;
constexpr int SH_ = 256;
constexpr int SW_ = 256;

// One thread per (n, h, w) output pixel; loop over the 32 channels reusing the
// bilinear coordinates/weights (they are channel-independent).
__global__ __launch_bounds__(256) void affine_sample_kernel(
    const float* __restrict__ x,      // (N, C, H, W)
    const float* __restrict__ params, // (N, 5): theta, sx, sy, tx, ty
    float* __restrict__ out)          // (N, C, SH, SW)
{
    const int idx = blockIdx.x * blockDim.x + threadIdx.x; // n*SH*SW + h*SW + w
    const int w = idx & (SW_ - 1);
    const int h = (idx >> 8) & (SH_ - 1);
    const int n = idx >> 16;

    // Affine matrix from params (wave-uniform: whole block shares one n here,
    // since SH*SW = 65536 is a multiple of blockDim).
    const float theta = params[n * 5 + 0];
    const float sx    = params[n * 5 + 1];
    const float sy    = params[n * 5 + 2];
    const float tx    = params[n * 5 + 3];
    const float ty    = params[n * 5 + 4];
    const float st = sinf(theta);
    const float ct = cosf(theta);
    const float a = sx * ct, b = -st, cc = tx;
    const float d = st,      e = sy * ct, f = ty;

    // ws = floor(w * (W/SW)) = 2w exactly; gx = (2*ws + 1)/W - 1
    const float gx = (2.0f * (float)(2 * w) + 1.0f) * (1.0f / (float)W_) - 1.0f;
    const float gy = (2.0f * (float)(2 * h) + 1.0f) * (1.0f / (float)H_) - 1.0f;

    const float sxp = a * gx + b * gy + cc;
    const float syp = d * gx + e * gy + f;
    const float ix = ((sxp + 1.0f) * (float)W_ - 1.0f) * 0.5f;
    const float iy = ((syp + 1.0f) * (float)H_ - 1.0f) * 0.5f;

    const float x0f = floorf(ix);
    const float y0f = floorf(iy);
    const float x1f = x0f + 1.0f;
    const float y1f = y0f + 1.0f;
    const float wx1 = ix - x0f, wx0 = 1.0f - wx1;
    const float wy1 = iy - y0f, wy0 = 1.0f - wy1;

    // Per-tap validity (zero-padding outside the image), matching the reference:
    // valid iff unclamped coord in [0, dim-1]; loads use clamped indices.
    const float vx0 = (x0f >= 0.0f && x0f <= (float)(W_ - 1)) ? 1.0f : 0.0f;
    const float vx1 = (x1f >= 0.0f && x1f <= (float)(W_ - 1)) ? 1.0f : 0.0f;
    const float vy0 = (y0f >= 0.0f && y0f <= (float)(H_ - 1)) ? 1.0f : 0.0f;
    const float vy1 = (y1f >= 0.0f && y1f <= (float)(H_ - 1)) ? 1.0f : 0.0f;

    const float w00 = wy0 * wx0 * vy0 * vx0;
    const float w01 = wy0 * wx1 * vy0 * vx1;
    const float w10 = wy1 * wx0 * vy1 * vx0;
    const float w11 = wy1 * wx1 * vy1 * vx1;

    int x0i = (int)x0f, y0i = (int)y0f;
    const int x0c = min(max(x0i, 0), W_ - 1);
    const int x1c = min(max(x0i + 1, 0), W_ - 1);
    const int y0c = min(max(y0i, 0), H_ - 1);
    const int y1c = min(max(y0i + 1, 0), H_ - 1);

    const int off00 = y0c * W_ + x0c;
    const int off01 = y0c * W_ + x1c;
    const int off10 = y1c * W_ + x0c;
    const int off11 = y1c * W_ + x1c;

    const float* __restrict__ p = x + (size_t)n * C_ * H_ * W_;
    float* __restrict__ o = out + ((size_t)n * C_ * SH_ + h) * SW_ + w;

#pragma unroll 4
    for (int c = 0; c < C_; ++c) {
        const float v00 = p[off00];
        const float v01 = p[off01];
        const float v10 = p[off10];
        const float v11 = p[off11];
        *o = v00 * w00 + v01 * w01 + v10 * w10 + v11 * w11;
        p += H_ * W_;
        o += SH_ * SW_;
    }
}

extern "C" void kernel_launch(void* const* d_in, const int* in_sizes, int n_in,
                              void* d_out, int out_size, void* d_ws, size_t ws_size,
                              hipStream_t stream) {
    const float* x      = (const float*)d_in[0];
    const float* params = (const float*)d_in[1];
    float* out = (float*)d_out;

    const int total = N_ * SH_ * SW_; // one thread per (n,h,w)
    const int block = 256;
    const int grid = total / block;   // 4096 blocks
    affine_sample_kernel<<<grid, block, 0, stream>>>(x, params, out);
}

// Round 2
// 786.101 us; speedup vs baseline: 1.1541x; 1.1541x over previous
//
#include <hip/hip_runtime.h>

// Problem shape (fixed): x (16,32,512,512) fp32, params (16,5) fp32,
// small_h = small_w = 256. Output (16,32,256,256) fp32.
constexpr int N_  = 16;
constexpr int C_  = 32;
constexpr int H_  = 512;
constexpr int W_  = 512;
constexpr int SH_ = 256;
constexpr int SW_ = 256;

// 2-D tile mapping: block = 16x16 output patch of one image n.
// A wave (64 lanes) covers 16 wide x 4 tall -> source taps cluster into
// ~8 source rows x ~32 px instead of a 64-px diagonal streak, cutting
// cachelines-per-load-instruction ~3-4x under rotation.
__global__ __launch_bounds__(256) void affine_sample_kernel(
    const float* __restrict__ x,      // (N, C, H, W)
    const float* __restrict__ params, // (N, 5): theta, sx, sy, tx, ty
    float* __restrict__ out)          // (N, C, SH, SW)
{
    const int w = blockIdx.x * 16 + threadIdx.x;
    const int h = blockIdx.y * 16 + threadIdx.y;
    const int n = blockIdx.z;

    // Affine params (wave-uniform: whole block shares one n).
    const float theta = params[n * 5 + 0];
    const float sx    = params[n * 5 + 1];
    const float sy    = params[n * 5 + 2];
    const float tx    = params[n * 5 + 3];
    const float ty    = params[n * 5 + 4];
    const float st = sinf(theta);
    const float ct = cosf(theta);
    const float a = sx * ct, b = -st, cc = tx;
    const float d = st,      e = sy * ct, f = ty;

    // ws = floor(w * (W/SW)) = 2w exactly; gx = (2*ws + 1)/W - 1
    const float gx = (2.0f * (float)(2 * w) + 1.0f) * (1.0f / (float)W_) - 1.0f;
    const float gy = (2.0f * (float)(2 * h) + 1.0f) * (1.0f / (float)H_) - 1.0f;

    const float sxp = a * gx + b * gy + cc;
    const float syp = d * gx + e * gy + f;
    const float ix = ((sxp + 1.0f) * (float)W_ - 1.0f) * 0.5f;
    const float iy = ((syp + 1.0f) * (float)H_ - 1.0f) * 0.5f;

    const float x0f = floorf(ix);
    const float y0f = floorf(iy);
    const float x1f = x0f + 1.0f;
    const float y1f = y0f + 1.0f;
    const float wx1 = ix - x0f, wx0 = 1.0f - wx1;
    const float wy1 = iy - y0f, wy0 = 1.0f - wy1;

    // Zero-padding validity (reference semantics): weight zeroed when the
    // UNclamped coord is outside [0, dim-1]; loads use clamped indices.
    const float vx0 = (x0f >= 0.0f && x0f <= (float)(W_ - 1)) ? 1.0f : 0.0f;
    const float vx1 = (x1f >= 0.0f && x1f <= (float)(W_ - 1)) ? 1.0f : 0.0f;
    const float vy0 = (y0f >= 0.0f && y0f <= (float)(H_ - 1)) ? 1.0f : 0.0f;
    const float vy1 = (y1f >= 0.0f && y1f <= (float)(H_ - 1)) ? 1.0f : 0.0f;

    const float w00 = wy0 * wx0 * vy0 * vx0;
    const float w01 = wy0 * wx1 * vy0 * vx1;
    const float w10 = wy1 * wx0 * vy1 * vx0;
    const float w11 = wy1 * wx1 * vy1 * vx1;

    const int x0i = (int)x0f, y0i = (int)y0f;
    const int x0c = min(max(x0i, 0), W_ - 1);
    const int x1c = min(max(x0i + 1, 0), W_ - 1);
    const int y0c = min(max(y0i, 0), H_ - 1);
    const int y1c = min(max(y0i + 1, 0), H_ - 1);

    const int off00 = y0c * W_ + x0c;
    const int off01 = y0c * W_ + x1c;
    const int off10 = y1c * W_ + x0c;
    const int off11 = y1c * W_ + x1c;

    const float* __restrict__ p = x + (size_t)n * C_ * H_ * W_;
    float* __restrict__ o = out + (((size_t)n * C_) * SH_ + h) * SW_ + w;

    // 8x unroll -> 32 loads in flight per thread for latency hiding.
#pragma unroll 8
    for (int c = 0; c < C_; ++c) {
        const float v00 = p[off00];
        const float v01 = p[off01];
        const float v10 = p[off10];
        const float v11 = p[off11];
        *o = v00 * w00 + v01 * w01 + v10 * w10 + v11 * w11;
        p += H_ * W_;
        o += SH_ * SW_;
    }
}

extern "C" void kernel_launch(void* const* d_in, const int* in_sizes, int n_in,
                              void* d_out, int out_size, void* d_ws, size_t ws_size,
                              hipStream_t stream) {
    const float* x      = (const float*)d_in[0];
    const float* params = (const float*)d_in[1];
    float* out = (float*)d_out;

    dim3 block(16, 16, 1);
    dim3 grid(SW_ / 16, SH_ / 16, N_); // 16 x 16 x 16 = 4096 blocks
    affine_sample_kernel<<<grid, block, 0, stream>>>(x, params, out);
}